// Round 5
// baseline (357.593 us; speedup 1.0000x reference)
//
#include <hip/hip_runtime.h>
#include <cstdint>

// Problem constants
#define Bn   32
#define Cn   256
#define Hn   56
#define Wn   56
#define HWn  (Hn*Wn)           // 3136
#define NPIX (Bn*HWn)          // 100352
#define WELEMS (Cn*Cn*9)       // 589824
#define EPSv 1e-5f

// padded channels-last activation plane: [b][58 rows][58 cols][256 ci] i8
// per-pixel 256B block stored XOR-swizzled: 16B slot s lives at s ^ (padded_col & 15)
#define PR   58
#define PPLANE (PR*PR)         // 3364

// ws layout (bytes)
#define F_WABS  0              // float index
#define F_SUM   64             // float[256]
#define F_SQ    320            // float[256]
#define STATS_BYTES 4096
#define WPK_OFF  4096                     // i8 wpk[kc=36][co=256][64]  (A repack)
#define WPK_BYTES WELEMS                  // 589824
#define ACT_OFF  (WPK_OFF + WPK_BYTES)    // 593920 (16B aligned)
#define ACT_BYTES (Bn*PPLANE*Cn)          // 27553792

typedef int v4i __attribute__((ext_vector_type(4)));

// ---------------------------------------------------------------------------
// Fused packing kernel (unchanged — verified rounds 3/4).
__global__ void pack_all(const float* __restrict__ x,
                         const float* __restrict__ w,
                         float* __restrict__ wsf,
                         uint8_t* __restrict__ wpk,
                         uint8_t* __restrict__ act) {
    if (blockIdx.x < 392) {
        int v = blockIdx.x * 256 + threadIdx.x;   // 0..100351
        // --- halo zeroing: 32 batches * 228 border pixels = 7296 ---
        if (v < 7296) {
            int b = v / 228;
            int r = v - b * 228;
            int y, xx;
            if (r < 58)       { y = 0;  xx = r; }
            else if (r < 116) { y = 57; xx = r - 58; }
            else { int r2 = r - 116; y = 1 + (r2 >> 1); xx = (r2 & 1) * 57; }
            uint4* d = (uint4*)(act + ((size_t)(b * PR + y) * PR + xx) * 256);
            uint4 z = make_uint4(0, 0, 0, 0);
            #pragma unroll
            for (int i = 0; i < 16; i++) d[i] = z;
        }
        // --- interior pack with per-pixel XOR swizzle ---
        int b = v / HWn;
        int p = v - b * HWn;
        int y = p / Wn;
        int xx = p - y * Wn;
        const float* xp = x + (size_t)b * Cn * HWn + p;
        int key = (xx + 1) & 15;
        uint32_t* dst = (uint32_t*)(act + ((size_t)(b * PR + (y + 1)) * PR + (xx + 1)) * 256);
        #pragma unroll
        for (int slot = 0; slot < 16; slot++) {
            uint32_t rr[4];
            #pragma unroll
            for (int cw = 0; cw < 4; cw++) {
                uint32_t r = 0;
                #pragma unroll
                for (int j = 0; j < 4; j++) {
                    uint32_t sgn = __float_as_uint(xp[(size_t)(slot * 16 + cw * 4 + j) * HWn]) >> 31;
                    r |= (sgn ? 0xFFu : 0x01u) << (j * 8);
                }
                rr[cw] = r;
            }
            *(uint4*)(dst + (size_t)((slot ^ key) * 4)) = make_uint4(rr[0], rr[1], rr[2], rr[3]);
        }
    } else {
        int u = (blockIdx.x - 392) * 256 + threadIdx.x;   // 36*256 = 9216
        int co = u / 36;
        int kc = u - co * 36;
        int t  = kc >> 2;          // tap
        int s  = kc & 3;           // 64-ci chunk
        const float* wp = w + (size_t)co * 2304 + t;      // OIHW
        uint32_t* dst = (uint32_t*)(wpk + ((size_t)kc * 256 + co) * 64);
        float sabs = 0.0f;
        #pragma unroll
        for (int cw = 0; cw < 16; cw++) {
            uint32_t r = 0;
            #pragma unroll
            for (int j = 0; j < 4; j++) {
                int ci = s * 64 + cw * 4 + j;
                float wv = wp[(size_t)ci * 9];
                sabs += fminf(fabsf(wv), 1.0f);
                r |= ((__float_as_uint(wv) >> 31) ? 0xFFu : 0x01u) << (j * 8);
            }
            dst[cw] = r;
        }
        #pragma unroll
        for (int off = 32; off; off >>= 1) sabs += __shfl_down(sabs, off);
        __shared__ float sh[4];
        if ((threadIdx.x & 63) == 0) sh[threadIdx.x >> 6] = sabs;
        __syncthreads();
        if (threadIdx.x == 0)
            atomicAdd(&wsf[F_WABS], sh[0] + sh[1] + sh[2] + sh[3]);
    }
}

// ---------------------------------------------------------------------------
// Binary conv as implicit GEMM on the i8 matrix pipe, LDS-staged B.
// Round-5: FULL dual software pipeline —
//   B-path: bfA/bfB register double-buffer; each step issues the 7 ds_reads
//     for step s+1 FIRST, then runs 28 MFMAs on the resident buffer (counted
//     lgkmcnt overlap; ~120cy LDS latency hidden under ~570cy of MFMA).
//   A-path: af0/af1 rotation, prefetch distance 2 K-steps (counted vmcnt).
//   Tap addresses updated incrementally (pixb += dtoff, key += ddw) to keep
//   total regs ~230 < 256 (2 waves/SIMD preserved).
__global__ __launch_bounds__(256, 2) void conv_mfma(
    const uint8_t* __restrict__ act, const uint8_t* __restrict__ wpk,
    const float* __restrict__ x, float* __restrict__ wsf,
    float* __restrict__ out) {
    __shared__ uint4 ldsv[3712];              // 59392 B
    uint8_t* lds = (uint8_t*)ldsv;

    const int tid  = threadIdx.x;
    const int lane = tid & 63;
    const int wid  = tid >> 6;                // 0..3
    const int l15  = lane & 15;
    const int l4   = lane >> 4;               // 0..3

    const int bx = blockIdx.x;                // 0..895
    const int b  = bx / 28;
    const int y0 = (bx - b * 28) * 2;         // first output image row

    // Stage padded rows y0..y0+3 = one contiguous 59392B block of act.
    {
        const uint4* src = (const uint4*)(act + ((size_t)b * PR + y0) * PR * 256);
        for (int i = tid; i < 3712; i += 256) ldsv[i] = src[i];
    }

    // A-fragment lane base (co = wid*64 + mi*16 + l15, bytes l4*16)
    const uint8_t* abase = wpk + (wid * 64 + l15) * 64 + l4 * 16;

    // A prologue: distance-2 rotation, fill with kc = 0, 1.
    v4i af0[4], af1[4];
    #pragma unroll
    for (int mi = 0; mi < 4; mi++) {
        af0[mi] = *(const v4i*)(abase + (size_t)0 * 16384 + mi * 1024);
        af1[mi] = *(const v4i*)(abase + (size_t)1 * 16384 + mi * 1024);
    }

    // Tap-walking state for t=0 (dh=-1, dw=-1): window corner (r_, c_) local.
    int pixb[7], key[7];
    #pragma unroll
    for (int ni = 0; ni < 7; ni++) {
        int n  = ni * 16 + l15;
        int r_ = n / 56;
        int c_ = n - r_ * 56;
        pixb[ni] = (r_ * 58 + c_) * 256;
        key[ni]  = c_ & 15;
    }

    __syncthreads();

    // B prologue: load (t=0, s=0) into bfA.
    v4i bfA[7], bfB[7];
    #pragma unroll
    for (int ni = 0; ni < 7; ni++)
        bfA[ni] = *(const v4i*)(lds + pixb[ni] + ((l4 ^ key[ni]) << 4));

    v4i acc[4][7] = {};

// STEP: prefetch bf for sub-step SP into BFN, MFMA on BFC with AF,
// then reload AF with K-chunk KCN (distance-2 ahead, clamped tail).
#define STEP(SP, BFC, BFN, AF, KCN)                                            \
    {                                                                          \
        _Pragma("unroll")                                                      \
        for (int ni = 0; ni < 7; ni++)                                         \
            BFN[ni] = *(const v4i*)(lds + pixb[ni] +                           \
                                    ((((SP) * 4 + l4) ^ key[ni]) << 4));       \
        _Pragma("unroll")                                                      \
        for (int ni = 0; ni < 7; ni++) {                                       \
            _Pragma("unroll")                                                  \
            for (int mi = 0; mi < 4; mi++)                                     \
                acc[mi][ni] = __builtin_amdgcn_mfma_i32_16x16x64_i8(           \
                    AF[mi], BFC[ni], acc[mi][ni], 0, 0, 0);                    \
        }                                                                      \
        {                                                                      \
            int kcn = (KCN) > 35 ? 35 : (KCN);                                 \
            const uint8_t* ap = abase + (size_t)kcn * 16384;                   \
            _Pragma("unroll")                                                  \
            for (int mi = 0; mi < 4; mi++)                                     \
                AF[mi] = *(const v4i*)(ap + mi * 1024);                        \
        }                                                                      \
    }

    #pragma unroll 1
    for (int t = 0; t < 9; t++) {
        const int t4 = t * 4;
        // Tap-walk delta t -> t+1: dw cycles -1,0,1 (ddw=+1, dtoff=+256),
        // wrapping at t=2,5 (ddw=-2, dtoff=(+58-2)*256); t=8 clamps (0).
        const int wrap  = (t == 2 || t == 5);
        const int dtoff = (t == 8) ? 0 : (wrap ? 56 * 256 : 256);
        const int ddw   = (t == 8) ? 0 : (wrap ? -2 : 1);

        STEP(1, bfA, bfB, af0, t4 + 2)      // consume (t,s0)
        STEP(2, bfB, bfA, af1, t4 + 3)      // consume (t,s1)
        STEP(3, bfA, bfB, af0, t4 + 4)      // consume (t,s2)
        // advance tap addresses to t+1 before prefetching (t+1, s0)
        #pragma unroll
        for (int ni = 0; ni < 7; ni++) {
            pixb[ni] += dtoff;
            key[ni]   = (key[ni] + ddw) & 15;
        }
        STEP(0, bfB, bfA, af1, t4 + 5)      // consume (t,s3), prefetch (t+1,s0)
    }
#undef STEP

    const float mv = wsf[F_WABS] * (1.0f / (float)WELEMS);
    const int co_w = wid * 64;
    const int pbase = b * (Cn * HWn) + y0 * 56;

    // Epilogue: scale + shortcut + store + per-channel partial stats.
    float ssum[4][4] = {}, ssq[4][4] = {};
    #pragma unroll
    for (int mi = 0; mi < 4; mi++) {
        #pragma unroll
        for (int ni = 0; ni < 7; ni++) {
            v4i a = acc[mi][ni];
            #pragma unroll
            for (int q = 0; q < 4; q++) {
                int co = co_w + mi * 16 + l4 * 4 + q;
                size_t idx = (size_t)pbase + (size_t)co * HWn + (ni * 16 + l15);
                float val = fmaf(mv, (float)a[q], x[idx]);
                out[idx] = val;
                ssum[mi][q] += val;
                ssq[mi][q]  += val * val;
            }
        }
    }
    // Reduce across the 16 lanes (l15) sharing each channel, then atomics.
    #pragma unroll
    for (int mi = 0; mi < 4; mi++) {
        #pragma unroll
        for (int q = 0; q < 4; q++) {
            float s = ssum[mi][q], sq = ssq[mi][q];
            #pragma unroll
            for (int off = 1; off < 16; off <<= 1) {
                s  += __shfl_xor(s, off);
                sq += __shfl_xor(sq, off);
            }
            if (l15 == 0) {
                int co = co_w + mi * 16 + l4 * 4 + q;
                atomicAdd(&wsf[F_SUM + co], s);
                atomicAdd(&wsf[F_SQ  + co], sq);
            }
        }
    }
}

// ---------------------------------------------------------------------------
// BN finalize (per-plane, from fused stats) + normalize + ReLU, in place.
__global__ void epilogue_kernel(float* __restrict__ out,
                                const float* __restrict__ wsf,
                                const float* __restrict__ g,
                                const float* __restrict__ bt) {
    int plane = blockIdx.x;   // b*256 + c
    int c = plane & 255;
    const float n = (float)(Bn * HWn);
    float mean = wsf[F_SUM + c] / n;
    float var  = wsf[F_SQ + c] / n - mean * mean;
    float sc = g[c] * rsqrtf(var + EPSv);
    float sh = bt[c] - mean * sc;
    float4* o4 = (float4*)(out + (size_t)plane * HWn);
    for (int i = threadIdx.x; i < HWn / 4; i += 256) {
        float4 v = o4[i];
        v.x = fmaxf(fmaf(v.x, sc, sh), 0.0f);
        v.y = fmaxf(fmaf(v.y, sc, sh), 0.0f);
        v.z = fmaxf(fmaf(v.z, sc, sh), 0.0f);
        v.w = fmaxf(fmaf(v.w, sc, sh), 0.0f);
        o4[i] = v;
    }
}

// ---------------------------------------------------------------------------
extern "C" void kernel_launch(void* const* d_in, const int* in_sizes, int n_in,
                              void* d_out, int out_size, void* d_ws, size_t ws_size,
                              hipStream_t stream) {
    const float* x     = (const float*)d_in[0];
    const float* w     = (const float*)d_in[1];
    const float* gamma = (const float*)d_in[2];
    const float* beta  = (const float*)d_in[3];
    float* out = (float*)d_out;

    float*   wsf = (float*)d_ws;
    uint8_t* wpk = (uint8_t*)d_ws + WPK_OFF;
    uint8_t* act = (uint8_t*)d_ws + ACT_OFF;

    hipMemsetAsync(d_ws, 0, STATS_BYTES, stream);
    pack_all<<<dim3(428), dim3(256), 0, stream>>>(x, w, wsf, wpk, act);
    conv_mfma<<<dim3(896), dim3(256), 0, stream>>>(act, wpk, x, wsf, out);
    epilogue_kernel<<<dim3(Bn * Cn), dim3(256), 0, stream>>>(out, wsf, gamma, beta);
}